// Round 1
// 87.026 us; speedup vs baseline: 1.1111x; 1.1111x over previous
//
#include <hip/hip_runtime.h>

#define NTH 256

#define PHI1 0.29504296f    // e^{-1.220703125}
#define PHI2 0.0075683594f  // e^{-4.8828125}
#define GCUT 18.0f          // Gaussian support cutoff: e^-18 = 1.5e-8

// Bank swizzle — conflict-free for all in-place strides; swz(i+128)=swz(i)+128
// so 128-aligned group regions preserve the pattern.
__device__ __forceinline__ int swz(int i) { return i ^ (((i >> 4) & 3) * 5); }

__device__ __forceinline__ float2 cmul(float2 a, float2 b) {
  return make_float2(a.x * b.x - a.y * b.y, a.x * b.y + a.y * b.x);
}

template <int W>
__device__ __forceinline__ float wsum(float v) {
#pragma unroll
  for (int off = 1; off < W; off <<= 1) v += __shfl_xor(v, off, 64);
  return v;
}

// P(idx): output frequency of storage slot idx after the DIF stage sequence.
template <int M>
__device__ __forceinline__ int prevM(int i) {
  if (M == 128)
    return ((i >> 5) & 3) | (((i >> 3) & 3) << 2) | (((i >> 1) & 3) << 4) | ((i & 1) << 6);
  else if (M == 256)
    return ((i & 3) << 6) | (((i >> 2) & 3) << 4) | (((i >> 4) & 3) << 2) | ((i >> 6) & 3);
  else if (M == 512)
    return ((i >> 7) & 3) | (((i >> 5) & 3) << 2) | (((i >> 3) & 3) << 4) |
           (((i >> 1) & 3) << 6) | ((i & 1) << 8);
  else if (M == 1024)
    return ((i >> 8) & 3) | (((i >> 6) & 3) << 2) | (((i >> 4) & 3) << 4) |
           (((i >> 2) & 3) << 6) | ((i & 3) << 8);
  else
    return ((i >> 9) & 3) | (((i >> 7) & 3) << 2) | (((i >> 5) & 3) << 4) |
           (((i >> 3) & 3) << 6) | (((i >> 1) & 3) << 8) | ((i & 1) << 10);
}

// In-place radix-4 DIF stage; twiddles in registers.
template <bool INV>
__device__ __forceinline__ void dif4(float2* A, int j, int ls, float astep) {
  const int s = 1 << ls;
  const int e = j & (s - 1);
  const int base = ((j >> ls) << (ls + 2)) | e;
  float2 w1;
  __sincosf(astep * (float)e, &w1.y, &w1.x);
  if (INV) w1.y = -w1.y;
  const float2 w2 = cmul(w1, w1);
  const float2 w3 = cmul(w2, w1);
  const float2 a0 = A[swz(base)];
  const float2 a1 = A[swz(base + s)];
  const float2 a2 = A[swz(base + 2 * s)];
  const float2 a3 = A[swz(base + 3 * s)];
  const float t0x = a0.x + a2.x, t0y = a0.y + a2.y;
  const float t1x = a0.x - a2.x, t1y = a0.y - a2.y;
  const float t2x = a1.x + a3.x, t2y = a1.y + a3.y;
  const float bdx = a1.x - a3.x, bdy = a1.y - a3.y;
  const float sgn = INV ? -1.0f : 1.0f;
  const float t3x = sgn * bdy, t3y = -sgn * bdx;
  A[swz(base)]         = make_float2(t0x + t2x, t0y + t2y);
  A[swz(base + s)]     = cmul(make_float2(t1x + t3x, t1y + t3y), w1);
  A[swz(base + 2 * s)] = cmul(make_float2(t0x - t2x, t0y - t2y), w2);
  A[swz(base + 3 * s)] = cmul(make_float2(t1x - t3x, t1y - t3y), w3);
}

// In-place radix-4 DIT stage (transpose network; forward only).
__device__ __forceinline__ void dit4(float2* A, int j, int ls, float astep) {
  const int s = 1 << ls;
  const int e = j & (s - 1);
  const int base = ((j >> ls) << (ls + 2)) | e;
  float2 w1;
  __sincosf(astep * (float)e, &w1.y, &w1.x);
  const float2 w2 = cmul(w1, w1);
  const float2 w3 = cmul(w2, w1);
  const float2 c0 = A[swz(base)];
  const float2 c1 = cmul(A[swz(base + s)], w1);
  const float2 c2 = cmul(A[swz(base + 2 * s)], w2);
  const float2 c3 = cmul(A[swz(base + 3 * s)], w3);
  const float t0x = c0.x + c2.x, t0y = c0.y + c2.y;
  const float t1x = c0.x - c2.x, t1y = c0.y - c2.y;
  const float t2x = c1.x + c3.x, t2y = c1.y + c3.y;
  const float bdx = c1.x - c3.x, bdy = c1.y - c3.y;
  const float t3x = bdy, t3y = -bdx;
  A[swz(base)]         = make_float2(t0x + t2x, t0y + t2y);
  A[swz(base + s)]     = make_float2(t1x + t3x, t1y + t3y);
  A[swz(base + 2 * s)] = make_float2(t0x - t2x, t0y - t2y);
  A[swz(base + 3 * s)] = make_float2(t1x - t3x, t1y - t3y);
}

__device__ __forceinline__ void r2pair(float2* A, int g) {
  const float2 a = A[swz(2 * g)];
  const float2 b = A[swz(2 * g + 1)];
  A[swz(2 * g)]     = make_float2(a.x + b.x, a.y + b.y);
  A[swz(2 * g + 1)] = make_float2(a.x - b.x, a.y - b.y);
}

template <int M> struct LMof { static constexpr int v =
  (M == 2048) ? 11 : (M == 1024) ? 10 : (M == 512) ? 9 : (M == 256) ? 8 : 7; };

// Block-wide in-place DIF: natural -> P-order. M in {1024, 2048}.
template <int M, bool INV>
__device__ __forceinline__ void dif_blk(float2* A) {
  constexpr int LM = LMof<M>::v;
  constexpr int NB = M / 4;
  const int tid = (int)threadIdx.x;
#pragma unroll
  for (int ls = LM - 2; ls >= (LM & 1); ls -= 2) {
    const float astep = -1.5707963267948966f / (float)(1 << ls);
    __syncthreads();
#pragma unroll
    for (int i = 0; i < NB / NTH; ++i) dif4<INV>(A, tid + NTH * i, ls, astep);
  }
  if (LM & 1) {
    __syncthreads();
#pragma unroll
    for (int i = 0; i < (M / 2) / NTH; ++i) r2pair(A, tid + NTH * i);
  }
  __syncthreads();
}

// Block-wide in-place DIT (forward): P-order -> natural.
template <int M>
__device__ __forceinline__ void dit_blk(float2* A) {
  constexpr int LM = LMof<M>::v;
  constexpr int NB = M / 4;
  const int tid = (int)threadIdx.x;
  if (LM & 1) {
    __syncthreads();
#pragma unroll
    for (int i = 0; i < (M / 2) / NTH; ++i) r2pair(A, tid + NTH * i);
  }
#pragma unroll
  for (int ls = (LM & 1); ls <= LM - 2; ls += 2) {
    const float astep = -1.5707963267948966f / (float)(1 << ls);
    __syncthreads();
#pragma unroll
    for (int i = 0; i < NB / NTH; ++i) dit4(A, tid + NTH * i, ls, astep);
  }
  __syncthreads();
}

// Lane-group FFTs, barrier-free (group-private slice, in-order LDS pipe).
template <int M, bool INV, int LANES>
__device__ __forceinline__ void dif_w(float2* Aw, int l) {
  constexpr int LM = LMof<M>::v;
  constexpr int NB = M / 4;
#pragma unroll
  for (int ls = LM - 2; ls >= (LM & 1); ls -= 2) {
    const float astep = -1.5707963267948966f / (float)(1 << ls);
#pragma unroll
    for (int i = 0; i < NB / LANES; ++i) dif4<INV>(Aw, l + LANES * i, ls, astep);
  }
  if (LM & 1) {
#pragma unroll
    for (int i = 0; i < (M / 2) / LANES; ++i) r2pair(Aw, l + LANES * i);
  }
}

template <int M, int LANES>
__device__ __forceinline__ void dit_w(float2* Aw, int l) {
  constexpr int LM = LMof<M>::v;
  constexpr int NB = M / 4;
  if (LM & 1) {
#pragma unroll
    for (int i = 0; i < (M / 2) / LANES; ++i) r2pair(Aw, l + LANES * i);
  }
#pragma unroll
  for (int ls = (LM & 1); ls <= LM - 2; ls += 2) {
    const float astep = -1.5707963267948966f / (float)(1 << ls);
#pragma unroll
    for (int i = 0; i < NB / LANES; ++i) dit4(Aw, l + LANES * i, ls, astep);
  }
}

// ---------------- Stage A: 2048-pt FFT per (b,c) signal ----------------
__global__ __launch_bounds__(NTH) void kA(const float* __restrict__ x,
                                          float2* __restrict__ xh) {
  __shared__ float2 A[2048];
  const int n = blockIdx.x, b = n / 6, c = n % 6;
  const float* xp = x + (size_t)b * (2048 * 6) + c;
#pragma unroll
  for (int i = 0; i < 8; ++i) {
    const int t = (int)threadIdx.x + NTH * i;
    A[swz(t)] = make_float2(xp[t * 6], 0.0f);
  }
  dif_blk<2048, false>(A);
#pragma unroll
  for (int i = 0; i < 8; ++i) {
    const int t = (int)threadIdx.x + NTH * i;
    xh[(size_t)n * 2048 + prevM<2048>(t)] = A[swz(t)];
  }
}

// ================= Fused B+C: parent first-order path, V kept in LDS =======

// Parent, block-wide, M1=1024 (j1 0..7). Leaves V (natural order, swizzled
// storage) intact in A. scr = separate small LDS scratch (NOT overlaid on A).
__device__ __forceinline__ void parent_blk1024(float2* A, float* scr,
                                               const float2* __restrict__ src,
                                               float* __restrict__ out,
                                               int b, int c, int j1) {
  constexpr int M1 = 1024;
  constexpr int NR = 4;
  const int tid = (int)threadIdx.x;
  const float xi = 0.4f * exp2f(-0.125f * (float)j1);
  const float sig = 0.1f * xi;
  const float i2s = 1.0f / (2.0f * sig * sig);
#pragma unroll
  for (int i = 0; i < NR; ++i) {
    const int m = tid + NTH * i;
    float2 acc = make_float2(0.0f, 0.0f);
#pragma unroll
    for (int q = 0; q < 2; ++q) {
      const int f = m + q * M1;
      const float fr = (float)(f < 1024 ? f : f - 2048) * (1.0f / 2048.0f);
      const float d = fr - xi;
      const float dd = d * d * i2s;
      if (dd < GCUT) {
        const float g = __expf(-dd);
        const float2 v = src[f];
        acc.x += v.x * g; acc.y += v.y * g;
      }
    }
    A[swz(m)] = acc;
  }
  dif_blk<M1, true>(A);
#pragma unroll
  for (int i = 0; i < NR; ++i) {
    const int m = tid + NTH * i;
    const float2 zv = A[swz(m)];
    A[swz(m)] = make_float2(sqrtf(zv.x * zv.x + zv.y * zv.y) * (1.0f / 2048.0f), 0.0f);
  }
  dit_blk<M1>(A);  // V natural (digit reversal cancels); KEEP in LDS.
  const float invM = 1.0f / (float)M1;
  const float c0 = A[0].x * invM;  // swz identity for idx<16
  const float2 U1 = A[1], U2 = A[2];
  const float k1 = PHI1 * 2.0f * invM, k2 = PHI2 * 2.0f * invM;
  float part = 0.0f;
#pragma unroll
  for (int i = 0; i < NR; ++i) {
    const int t = tid + NTH * i;
    float sv, cv;
    __sincosf((6.283185307179586f / (float)M1) * (float)t, &sv, &cv);
    float acc = c0 + k1 * (U1.x * cv - U1.y * sv);
    const float c2 = cv * cv - sv * sv, s2 = 2.0f * sv * cv;
    acc += k2 * (U2.x * c2 - U2.y * s2);
    part += __logf(acc + 1e-6f);
  }
  part = wsum<64>(part);
  const int lane = tid & 63, wid = tid >> 6;
  if (lane == 0) scr[wid] = part;
  __syncthreads();
  if (tid == 0)
    out[((size_t)b * 440 + j1) * 6 + c] = (scr[0] + scr[1] + scr[2] + scr[3]) * invM;
}

// Parent, per-wave (64 lanes), M1 in {512, 256}. V stays in Aw.
template <int M1>
__device__ __forceinline__ void parent_wav(float2* Aw, const float2* __restrict__ src,
                                           float* __restrict__ out,
                                           int b, int c, int j1, int l) {
  constexpr int NRW = M1 / 64;
  constexpr int F = 2048 / M1;
  const float xi = 0.4f * exp2f(-0.125f * (float)j1);
  const float sig = 0.1f * xi;
  const float i2s = 1.0f / (2.0f * sig * sig);
#pragma unroll
  for (int i = 0; i < NRW; ++i) {
    const int m = l + 64 * i;
    float2 acc = make_float2(0.0f, 0.0f);
#pragma unroll
    for (int q = 0; q < F; ++q) {
      const int f = m + q * M1;
      const float fr = (float)(f < 1024 ? f : f - 2048) * (1.0f / 2048.0f);
      const float d = fr - xi;
      const float dd = d * d * i2s;
      if (dd < GCUT) {
        const float g = __expf(-dd);
        const float2 v = src[f];
        acc.x += v.x * g; acc.y += v.y * g;
      }
    }
    Aw[swz(m)] = acc;
  }
  dif_w<M1, true, 64>(Aw, l);
#pragma unroll
  for (int i = 0; i < NRW; ++i) {
    const int m = l + 64 * i;
    const float2 zv = Aw[swz(m)];
    Aw[swz(m)] = make_float2(sqrtf(zv.x * zv.x + zv.y * zv.y) * (1.0f / 2048.0f), 0.0f);
  }
  dit_w<M1, 64>(Aw, l);  // V natural; KEEP.
  const float invM = 1.0f / (float)M1;
  const float c0 = Aw[0].x * invM;
  const float2 U1 = Aw[1], U2 = Aw[2];
  const float k1 = PHI1 * 2.0f * invM, k2 = PHI2 * 2.0f * invM;
  float part = 0.0f;
#pragma unroll
  for (int i = 0; i < NRW; ++i) {
    const int t = l + 64 * i;
    float sv, cv;
    __sincosf((6.283185307179586f / (float)M1) * (float)t, &sv, &cv);
    float acc = c0 + k1 * (U1.x * cv - U1.y * sv);
    const float c2 = cv * cv - sv * sv, s2 = 2.0f * sv * cv;
    acc += k2 * (U2.x * c2 - U2.y * s2);
    part += __logf(acc + 1e-6f);
  }
  part = wsum<64>(part);
  if (l == 0) out[((size_t)b * 440 + j1) * 6 + c] = part * invM;
}

// Parent, per-half-wave (32 lanes), M1=128. V stays in Ah.
__device__ __forceinline__ void parent_dual(float2* Ah, const float2* __restrict__ src,
                                            float* __restrict__ out,
                                            int b, int c, int j1, int ll) {
  const float xi = 0.4f * exp2f(-0.125f * (float)j1);
  const float sig = 0.1f * xi;
  const float i2s = 1.0f / (2.0f * sig * sig);
#pragma unroll
  for (int i = 0; i < 4; ++i) {
    const int m = ll + 32 * i;
    float2 acc = make_float2(0.0f, 0.0f);
#pragma unroll
    for (int q = 0; q < 16; ++q) {
      const int f = m + q * 128;
      const float fr = (float)(f < 1024 ? f : f - 2048) * (1.0f / 2048.0f);
      const float d = fr - xi;
      const float dd = d * d * i2s;
      if (dd < GCUT) {
        const float g = __expf(-dd);
        const float2 v = src[f];
        acc.x += v.x * g; acc.y += v.y * g;
      }
    }
    Ah[swz(m)] = acc;
  }
  dif_w<128, true, 32>(Ah, ll);
#pragma unroll
  for (int i = 0; i < 4; ++i) {
    const int m = ll + 32 * i;
    const float2 zv = Ah[swz(m)];
    Ah[swz(m)] = make_float2(sqrtf(zv.x * zv.x + zv.y * zv.y) * (1.0f / 2048.0f), 0.0f);
  }
  dit_w<128, 32>(Ah, ll);  // V natural; KEEP.
  const float invM = 1.0f / 128.0f;
  const float c0 = Ah[0].x * invM;
  const float2 U1 = Ah[1], U2 = Ah[2];
  const float k1 = PHI1 * 2.0f * invM, k2 = PHI2 * 2.0f * invM;
  float part = 0.0f;
#pragma unroll
  for (int i = 0; i < 4; ++i) {
    const int t = ll + 32 * i;
    float sv, cv;
    __sincosf((6.283185307179586f / 128.0f) * (float)t, &sv, &cv);
    float acc = c0 + k1 * (U1.x * cv - U1.y * sv);
    const float c2 = cv * cv - sv * sv, s2 = 2.0f * sv * cv;
    acc += k2 * (U2.x * c2 - U2.y * s2);
    part += __logf(acc + 1e-6f);
  }
  part = wsum<32>(part);
  if (ll == 0) out[((size_t)b * 440 + j1) * 6 + c] = part * invM;
}

// Descendant (second order), per-wave (64 lanes). V read from LDS (swizzled).
template <int M2>
__device__ __forceinline__ void desc_wav(float2* Aw, const float2* __restrict__ Vl,
                                         float* __restrict__ outp, int M1, int F,
                                         float xi, int l) {
  constexpr int NR2 = M2 / 64;
  const float sg = 0.8f * xi;
  const float i2s = 1.0f / (2.0f * sg * sg);
#pragma unroll
  for (int ii = 0; ii < NR2; ++ii) {
    const int m = l + 64 * ii;
    float2 acc = make_float2(0.0f, 0.0f);
    for (int q = 0; q < F; ++q) {
      const int f = m + q * M2;
      const float fr = (float)(f < (M1 >> 1) ? f : f - M1) * (1.0f / 2048.0f);
      const float d = fr - xi;
      const float dd = d * d * i2s;
      if (dd < GCUT) {
        const float g = __expf(-dd);
        const float2 vv = Vl[swz(f)];
        acc.x += vv.x * g; acc.y += vv.y * g;
      }
    }
    Aw[swz(m)] = acc;
  }
  dif_w<M2, true, 64>(Aw, l);
  const float invM1f = 1.0f / (float)M1;
  float cvs[NR2], svs[NR2];
  float b0 = 0, b1r = 0, b1i = 0, b2r = 0, b2i = 0;
#pragma unroll
  for (int ii = 0; ii < NR2; ++ii) {
    const int idx = l + 64 * ii;
    const float2 zv = Aw[swz(idx)];
    const float u = sqrtf(zv.x * zv.x + zv.y * zv.y) * invM1f;
    const int t = prevM<M2>(idx);
    float sv, cv;
    __sincosf((6.283185307179586f / (float)M2) * (float)t, &sv, &cv);
    cvs[ii] = cv; svs[ii] = sv;
    b0 += u;
    b1r += u * cv; b1i -= u * sv;
    const float c2 = cv * cv - sv * sv, s2 = 2.0f * sv * cv;
    b2r += u * c2; b2i -= u * s2;
  }
  b0 = wsum<64>(b0);
  b1r = wsum<64>(b1r); b1i = wsum<64>(b1i);
  b2r = wsum<64>(b2r); b2i = wsum<64>(b2i);
  const float k1 = 2.0f * PHI1, k2 = 2.0f * PHI2;
  const float invM2 = 1.0f / (float)M2;
  float part = 0.0f;
#pragma unroll
  for (int ii = 0; ii < NR2; ++ii) {
    const float cv = cvs[ii], sv = svs[ii];
    float acc = b0 + k1 * (b1r * cv - b1i * sv);
    const float c2 = cv * cv - sv * sv, s2 = 2.0f * sv * cv;
    acc += k2 * (b2r * c2 - b2i * s2);
    part += __logf(acc * invM2 + 1e-6f);
  }
  part = wsum<64>(part);
  if (l == 0) *outp = part * invM2;
}

// Descendant, per-half-wave (32 lanes), M2=128. V from LDS (swizzled).
__device__ __forceinline__ void desc_dual(float2* Ah, const float2* __restrict__ Vl,
                                          float* __restrict__ outp, int M1, int F,
                                          float xi, int ll) {
  const float sg = 0.8f * xi;
  const float i2s = 1.0f / (2.0f * sg * sg);
#pragma unroll
  for (int ii = 0; ii < 4; ++ii) {
    const int m = ll + 32 * ii;
    float2 acc = make_float2(0.0f, 0.0f);
    for (int q = 0; q < F; ++q) {
      const int f = m + q * 128;
      const float fr = (float)(f < (M1 >> 1) ? f : f - M1) * (1.0f / 2048.0f);
      const float d = fr - xi;
      const float dd = d * d * i2s;
      if (dd < GCUT) {
        const float g = __expf(-dd);
        const float2 vv = Vl[swz(f)];
        acc.x += vv.x * g; acc.y += vv.y * g;
      }
    }
    Ah[swz(m)] = acc;
  }
  dif_w<128, true, 32>(Ah, ll);
  const float invM1f = 1.0f / (float)M1;
  float cvs[4], svs[4];
  float b0 = 0, b1r = 0, b1i = 0, b2r = 0, b2i = 0;
#pragma unroll
  for (int ii = 0; ii < 4; ++ii) {
    const int idx = ll + 32 * ii;
    const float2 zv = Ah[swz(idx)];
    const float u = sqrtf(zv.x * zv.x + zv.y * zv.y) * invM1f;
    const int t = prevM<128>(idx);
    float sv, cv;
    __sincosf((6.283185307179586f / 128.0f) * (float)t, &sv, &cv);
    cvs[ii] = cv; svs[ii] = sv;
    b0 += u;
    b1r += u * cv; b1i -= u * sv;
    const float c2 = cv * cv - sv * sv, s2 = 2.0f * sv * cv;
    b2r += u * c2; b2i -= u * s2;
  }
  b0 = wsum<32>(b0);
  b1r = wsum<32>(b1r); b1i = wsum<32>(b1i);
  b2r = wsum<32>(b2r); b2i = wsum<32>(b2i);
  const float k1 = 2.0f * PHI1, k2 = 2.0f * PHI2;
  const float invM2 = 1.0f / 128.0f;
  float part = 0.0f;
#pragma unroll
  for (int ii = 0; ii < 4; ++ii) {
    const float cv = cvs[ii], sv = svs[ii];
    float acc = b0 + k1 * (b1r * cv - b1i * sv);
    const float c2 = cv * cv - sv * sv, s2 = 2.0f * sv * cv;
    acc += k2 * (b2r * c2 - b2i * s2);
    part += __logf(acc * invM2 + 1e-6f);
  }
  part = wsum<32>(part);
  if (ll == 0) *outp = part * invM2;
}

// S2 output pointer for pair (j1, k): p = 4k(k-1)+j1.
__device__ __forceinline__ float* o2p(float* out, int b, int c, int j1, int k) {
  return out + ((size_t)b * 440 + 80 + 4 * k * (k - 1) + j1) * 6 + c;
}
__device__ __forceinline__ float xi2f(int k) { return 0.4f * exp2f(-(float)k); }

// kBC: 19 classes/signal. ci map (heavy-serial first):
//  [0,2)  o=1 (M1=512):  4 j1 per block (wave-private), j1 = 8+4*ci+wid.
//         desc: k2(512), k3(256) full-wave; k4..k9 (128) split 3/3 on halves.
//  [2,4)  o=2 (M1=256):  j1 = 16+4*(ci-2)+wid. desc: k3(256); k4..k9 split 3/3.
//  [4,12) o=0 (M1=1024): block-wide parent, j1 = ci-4.
//         desc: w0:{k1(1024)} w1:{k2(512),k5/k6} w2:{k3(512),k7/k8}
//               w3:{k4(256), h0:k9}.
//  [12,19) o=3..9 (M1=128): 8 paths/block on half-waves, j1 = 8o+2*wid+h;
//         desc k=o+1..9, all 128-pt, per-half.
// LDS: 4096 float2 = 32 KB (o=1 class uses all of it) -> 4-5 blocks/CU;
// grid needs only 912/256 = 3.6 blocks/CU, so residency is not the cap.
__global__ __launch_bounds__(NTH, 4) void kBC(const float2* __restrict__ xh,
                                              float* __restrict__ out) {
  __shared__ float2 L[4096];  // 32768 B
  const int ci = (int)blockIdx.x / 48;
  const int n  = (int)blockIdx.x % 48;
  const int b = n / 6, c = n % 6;
  const float2* src = xh + (size_t)n * 2048;
  const int tid = (int)threadIdx.x;
  const int wid = tid >> 6, l = tid & 63;
  const int h = l >> 5, ll = l & 31;

  if (ci < 2) {  // ---- o=1, M1=512, wave-private ----
    const int j1 = 8 + 4 * ci + wid;
    float2* Aw = L + wid * 1024;   // parent V: [0,512) of slice
    float2* W  = Aw + 512;         // descendant work: [512,1024)
    parent_wav<512>(Aw, src, out, b, c, j1, l);
    desc_wav<512>(W, Aw, o2p(out, b, c, j1, 2), 512, 1, xi2f(2), l);
    desc_wav<256>(W, Aw, o2p(out, b, c, j1, 3), 512, 2, xi2f(3), l);
    float2* Wh = W + h * 128;
    for (int i = 0; i < 3; ++i) {
      const int k = 4 + 2 * i + h;  // h0: k4,k6,k8  h1: k5,k7,k9
      desc_dual(Wh, Aw, o2p(out, b, c, j1, k), 512, 4, xi2f(k), ll);
    }
  } else if (ci < 4) {  // ---- o=2, M1=256, wave-private ----
    const int j1 = 16 + 4 * (ci - 2) + wid;
    float2* Aw = L + wid * 512;
    float2* W  = Aw + 256;
    parent_wav<256>(Aw, src, out, b, c, j1, l);
    desc_wav<256>(W, Aw, o2p(out, b, c, j1, 3), 256, 1, xi2f(3), l);
    float2* Wh = W + h * 128;
    for (int i = 0; i < 3; ++i) {
      const int k = 4 + 2 * i + h;
      desc_dual(Wh, Aw, o2p(out, b, c, j1, k), 256, 2, xi2f(k), ll);
    }
  } else if (ci < 12) {  // ---- o=0, M1=1024, block-wide parent ----
    const int j1 = ci - 4;
    float* scr = (float*)(L + 3968);  // [3968,4096) reserved for scratch
    parent_blk1024(L, scr, src, out, b, c, j1);
    // parent ends after a block-wide __syncthreads; V final in L[0,1024).
    if (wid == 0) {
      desc_wav<1024>(L + 1024, L, o2p(out, b, c, j1, 1), 1024, 1, xi2f(1), l);
    } else if (wid == 1) {
      desc_wav<512>(L + 2048, L, o2p(out, b, c, j1, 2), 1024, 2, xi2f(2), l);
      const int k = 5 + h;
      desc_dual(L + 3328 + h * 128, L, o2p(out, b, c, j1, k), 1024, 8, xi2f(k), ll);
    } else if (wid == 2) {
      desc_wav<512>(L + 2560, L, o2p(out, b, c, j1, 3), 1024, 2, xi2f(3), l);
      const int k = 7 + h;
      desc_dual(L + 3584 + h * 128, L, o2p(out, b, c, j1, k), 1024, 8, xi2f(k), ll);
    } else {
      desc_wav<256>(L + 3072, L, o2p(out, b, c, j1, 4), 1024, 4, xi2f(4), l);
      if (h == 0)
        desc_dual(L + 3840, L, o2p(out, b, c, j1, 9), 1024, 8, xi2f(9), ll);
    }
  } else {  // ---- o=3..9, M1=128, half-wave-private ----
    const int o = ci - 9;  // 3..9
    const int j1 = 8 * o + 2 * wid + h;
    float2* Ah = L + (2 * wid + h) * 256;  // parent [0,128), work [128,256)
    parent_dual(Ah, src, out, b, c, j1, ll);
    float2* W = Ah + 128;
    for (int k = o + 1; k <= 9; ++k)
      desc_dual(W, Ah, o2p(out, b, c, j1, k), 128, 1, xi2f(k), ll);
  }
}

extern "C" void kernel_launch(void* const* d_in, const int* in_sizes, int n_in,
                              void* d_out, int out_size, void* d_ws, size_t ws_size,
                              hipStream_t stream) {
  (void)in_sizes; (void)n_in; (void)out_size; (void)ws_size;
  const float* x = (const float*)d_in[0];  // [8, 2048, 6] fp32
  float* out = (float*)d_out;              // [8, 440, 6] fp32
  float2* xh = (float2*)d_ws;              // 48 * 2048 * 8 B = 786 KB
  kA<<<dim3(48), dim3(NTH), 0, stream>>>(x, xh);
  kBC<<<dim3(19 * 48), dim3(NTH), 0, stream>>>(xh, out);
}

// Round 2
// 85.739 us; speedup vs baseline: 1.1278x; 1.0150x over previous
//
#include <hip/hip_runtime.h>

#define NTH 256

#define PHI1 0.29504296f    // e^{-1.220703125}
#define PHI2 0.0075683594f  // e^{-4.8828125}
#define GCUT 18.0f          // Gaussian support cutoff: e^-18 = 1.5e-8

// Bank swizzle — conflict-free for all in-place strides; swz(i+128)=swz(i)+128
// so 128-aligned group regions preserve the pattern.
__device__ __forceinline__ int swz(int i) { return i ^ (((i >> 4) & 3) * 5); }

__device__ __forceinline__ float2 cmul(float2 a, float2 b) {
  return make_float2(a.x * b.x - a.y * b.y, a.x * b.y + a.y * b.x);
}

template <int W>
__device__ __forceinline__ float wsum(float v) {
#pragma unroll
  for (int off = 1; off < W; off <<= 1) v += __shfl_xor(v, off, 64);
  return v;
}

// P(idx): output frequency of storage slot idx after the DIF stage sequence.
template <int M>
__device__ __forceinline__ int prevM(int i) {
  if (M == 128)
    return ((i >> 5) & 3) | (((i >> 3) & 3) << 2) | (((i >> 1) & 3) << 4) | ((i & 1) << 6);
  else if (M == 256)
    return ((i & 3) << 6) | (((i >> 2) & 3) << 4) | (((i >> 4) & 3) << 2) | ((i >> 6) & 3);
  else if (M == 512)
    return ((i >> 7) & 3) | (((i >> 5) & 3) << 2) | (((i >> 3) & 3) << 4) |
           (((i >> 1) & 3) << 6) | ((i & 1) << 8);
  else if (M == 1024)
    return ((i >> 8) & 3) | (((i >> 6) & 3) << 2) | (((i >> 4) & 3) << 4) |
           (((i >> 2) & 3) << 6) | ((i & 3) << 8);
  else
    return ((i >> 9) & 3) | (((i >> 7) & 3) << 2) | (((i >> 5) & 3) << 4) |
           (((i >> 3) & 3) << 6) | (((i >> 1) & 3) << 8) | ((i & 1) << 10);
}

// In-place radix-4 DIF stage; twiddles in registers.
template <bool INV>
__device__ __forceinline__ void dif4(float2* A, int j, int ls, float astep) {
  const int s = 1 << ls;
  const int e = j & (s - 1);
  const int base = ((j >> ls) << (ls + 2)) | e;
  float2 w1;
  __sincosf(astep * (float)e, &w1.y, &w1.x);
  if (INV) w1.y = -w1.y;
  const float2 w2 = cmul(w1, w1);
  const float2 w3 = cmul(w2, w1);
  const float2 a0 = A[swz(base)];
  const float2 a1 = A[swz(base + s)];
  const float2 a2 = A[swz(base + 2 * s)];
  const float2 a3 = A[swz(base + 3 * s)];
  const float t0x = a0.x + a2.x, t0y = a0.y + a2.y;
  const float t1x = a0.x - a2.x, t1y = a0.y - a2.y;
  const float t2x = a1.x + a3.x, t2y = a1.y + a3.y;
  const float bdx = a1.x - a3.x, bdy = a1.y - a3.y;
  const float sgn = INV ? -1.0f : 1.0f;
  const float t3x = sgn * bdy, t3y = -sgn * bdx;
  A[swz(base)]         = make_float2(t0x + t2x, t0y + t2y);
  A[swz(base + s)]     = cmul(make_float2(t1x + t3x, t1y + t3y), w1);
  A[swz(base + 2 * s)] = cmul(make_float2(t0x - t2x, t0y - t2y), w2);
  A[swz(base + 3 * s)] = cmul(make_float2(t1x - t3x, t1y - t3y), w3);
}

// In-place radix-4 DIT stage (transpose network; forward only).
__device__ __forceinline__ void dit4(float2* A, int j, int ls, float astep) {
  const int s = 1 << ls;
  const int e = j & (s - 1);
  const int base = ((j >> ls) << (ls + 2)) | e;
  float2 w1;
  __sincosf(astep * (float)e, &w1.y, &w1.x);
  const float2 w2 = cmul(w1, w1);
  const float2 w3 = cmul(w2, w1);
  const float2 c0 = A[swz(base)];
  const float2 c1 = cmul(A[swz(base + s)], w1);
  const float2 c2 = cmul(A[swz(base + 2 * s)], w2);
  const float2 c3 = cmul(A[swz(base + 3 * s)], w3);
  const float t0x = c0.x + c2.x, t0y = c0.y + c2.y;
  const float t1x = c0.x - c2.x, t1y = c0.y - c2.y;
  const float t2x = c1.x + c3.x, t2y = c1.y + c3.y;
  const float bdx = c1.x - c3.x, bdy = c1.y - c3.y;
  const float t3x = bdy, t3y = -bdx;
  A[swz(base)]         = make_float2(t0x + t2x, t0y + t2y);
  A[swz(base + s)]     = make_float2(t1x + t3x, t1y + t3y);
  A[swz(base + 2 * s)] = make_float2(t0x - t2x, t0y - t2y);
  A[swz(base + 3 * s)] = make_float2(t1x - t3x, t1y - t3y);
}

__device__ __forceinline__ void r2pair(float2* A, int g) {
  const float2 a = A[swz(2 * g)];
  const float2 b = A[swz(2 * g + 1)];
  A[swz(2 * g)]     = make_float2(a.x + b.x, a.y + b.y);
  A[swz(2 * g + 1)] = make_float2(a.x - b.x, a.y - b.y);
}

template <int M> struct LMof { static constexpr int v =
  (M == 2048) ? 11 : (M == 1024) ? 10 : (M == 512) ? 9 : (M == 256) ? 8 : 7; };

// Block-wide in-place DIF: natural -> P-order. M in {1024, 2048}.
template <int M, bool INV>
__device__ __forceinline__ void dif_blk(float2* A) {
  constexpr int LM = LMof<M>::v;
  constexpr int NB = M / 4;
  const int tid = (int)threadIdx.x;
#pragma unroll
  for (int ls = LM - 2; ls >= (LM & 1); ls -= 2) {
    const float astep = -1.5707963267948966f / (float)(1 << ls);
    __syncthreads();
#pragma unroll
    for (int i = 0; i < NB / NTH; ++i) dif4<INV>(A, tid + NTH * i, ls, astep);
  }
  if (LM & 1) {
    __syncthreads();
#pragma unroll
    for (int i = 0; i < (M / 2) / NTH; ++i) r2pair(A, tid + NTH * i);
  }
  __syncthreads();
}

// Block-wide in-place DIT (forward): P-order -> natural.
template <int M>
__device__ __forceinline__ void dit_blk(float2* A) {
  constexpr int LM = LMof<M>::v;
  constexpr int NB = M / 4;
  const int tid = (int)threadIdx.x;
  if (LM & 1) {
    __syncthreads();
#pragma unroll
    for (int i = 0; i < (M / 2) / NTH; ++i) r2pair(A, tid + NTH * i);
  }
#pragma unroll
  for (int ls = (LM & 1); ls <= LM - 2; ls += 2) {
    const float astep = -1.5707963267948966f / (float)(1 << ls);
    __syncthreads();
#pragma unroll
    for (int i = 0; i < NB / NTH; ++i) dit4(A, tid + NTH * i, ls, astep);
  }
  __syncthreads();
}

// Lane-group FFTs, barrier-free (group-private slice, in-order LDS pipe).
template <int M, bool INV, int LANES>
__device__ __forceinline__ void dif_w(float2* Aw, int l) {
  constexpr int LM = LMof<M>::v;
  constexpr int NB = M / 4;
#pragma unroll
  for (int ls = LM - 2; ls >= (LM & 1); ls -= 2) {
    const float astep = -1.5707963267948966f / (float)(1 << ls);
#pragma unroll
    for (int i = 0; i < NB / LANES; ++i) dif4<INV>(Aw, l + LANES * i, ls, astep);
  }
  if (LM & 1) {
#pragma unroll
    for (int i = 0; i < (M / 2) / LANES; ++i) r2pair(Aw, l + LANES * i);
  }
}

template <int M, int LANES>
__device__ __forceinline__ void dit_w(float2* Aw, int l) {
  constexpr int LM = LMof<M>::v;
  constexpr int NB = M / 4;
  if (LM & 1) {
#pragma unroll
    for (int i = 0; i < (M / 2) / LANES; ++i) r2pair(Aw, l + LANES * i);
  }
#pragma unroll
  for (int ls = (LM & 1); ls <= LM - 2; ls += 2) {
    const float astep = -1.5707963267948966f / (float)(1 << ls);
#pragma unroll
    for (int i = 0; i < NB / LANES; ++i) dit4(Aw, l + LANES * i, ls, astep);
  }
}

// ---------------- Stage A: 2048-pt FFT per (b,c) signal ----------------
__global__ __launch_bounds__(NTH) void kA(const float* __restrict__ x,
                                          float2* __restrict__ xh) {
  __shared__ float2 A[2048];
  const int n = blockIdx.x, b = n / 6, c = n % 6;
  const float* xp = x + (size_t)b * (2048 * 6) + c;
#pragma unroll
  for (int i = 0; i < 8; ++i) {
    const int t = (int)threadIdx.x + NTH * i;
    A[swz(t)] = make_float2(xp[t * 6], 0.0f);
  }
  dif_blk<2048, false>(A);
#pragma unroll
  for (int i = 0; i < 8; ++i) {
    const int t = (int)threadIdx.x + NTH * i;
    xh[(size_t)n * 2048 + prevM<2048>(t)] = A[swz(t)];
  }
}

// ================= Fused B+C: parent first-order path, V kept in LDS =======

// Parent, block-wide, M1=1024 (j1 0..7). Leaves V (natural order, swizzled
// storage) intact in A. scr = separate small LDS scratch (NOT overlaid on A).
__device__ __forceinline__ void parent_blk1024(float2* A, float* scr,
                                               const float2* __restrict__ src,
                                               float* __restrict__ out,
                                               int b, int c, int j1) {
  constexpr int M1 = 1024;
  constexpr int NR = 4;
  const int tid = (int)threadIdx.x;
  const float xi = 0.4f * exp2f(-0.125f * (float)j1);
  const float sig = 0.1f * xi;
  const float i2s = 1.0f / (2.0f * sig * sig);
#pragma unroll
  for (int i = 0; i < NR; ++i) {
    const int m = tid + NTH * i;
    float2 acc = make_float2(0.0f, 0.0f);
#pragma unroll
    for (int q = 0; q < 2; ++q) {
      const int f = m + q * M1;
      const float fr = (float)(f < 1024 ? f : f - 2048) * (1.0f / 2048.0f);
      const float d = fr - xi;
      const float dd = d * d * i2s;
      if (dd < GCUT) {
        const float g = __expf(-dd);
        const float2 v = src[f];
        acc.x += v.x * g; acc.y += v.y * g;
      }
    }
    A[swz(m)] = acc;
  }
  dif_blk<M1, true>(A);
#pragma unroll
  for (int i = 0; i < NR; ++i) {
    const int m = tid + NTH * i;
    const float2 zv = A[swz(m)];
    A[swz(m)] = make_float2(sqrtf(zv.x * zv.x + zv.y * zv.y) * (1.0f / 2048.0f), 0.0f);
  }
  dit_blk<M1>(A);  // V natural (digit reversal cancels); KEEP in LDS.
  const float invM = 1.0f / (float)M1;
  const float c0 = A[0].x * invM;  // swz identity for idx<16
  const float2 U1 = A[1], U2 = A[2];
  const float k1 = PHI1 * 2.0f * invM, k2 = PHI2 * 2.0f * invM;
  float part = 0.0f;
#pragma unroll
  for (int i = 0; i < NR; ++i) {
    const int t = tid + NTH * i;
    float sv, cv;
    __sincosf((6.283185307179586f / (float)M1) * (float)t, &sv, &cv);
    float acc = c0 + k1 * (U1.x * cv - U1.y * sv);
    const float c2 = cv * cv - sv * sv, s2 = 2.0f * sv * cv;
    acc += k2 * (U2.x * c2 - U2.y * s2);
    part += __logf(acc + 1e-6f);
  }
  part = wsum<64>(part);
  const int lane = tid & 63, wid = tid >> 6;
  if (lane == 0) scr[wid] = part;
  __syncthreads();
  if (tid == 0)
    out[((size_t)b * 440 + j1) * 6 + c] = (scr[0] + scr[1] + scr[2] + scr[3]) * invM;
}

// Parent, per-wave (64 lanes), M1 in {512, 256}. V stays in Aw.
template <int M1>
__device__ __forceinline__ void parent_wav(float2* Aw, const float2* __restrict__ src,
                                           float* __restrict__ out,
                                           int b, int c, int j1, int l) {
  constexpr int NRW = M1 / 64;
  constexpr int F = 2048 / M1;
  const float xi = 0.4f * exp2f(-0.125f * (float)j1);
  const float sig = 0.1f * xi;
  const float i2s = 1.0f / (2.0f * sig * sig);
#pragma unroll
  for (int i = 0; i < NRW; ++i) {
    const int m = l + 64 * i;
    float2 acc = make_float2(0.0f, 0.0f);
#pragma unroll
    for (int q = 0; q < F; ++q) {
      const int f = m + q * M1;
      const float fr = (float)(f < 1024 ? f : f - 2048) * (1.0f / 2048.0f);
      const float d = fr - xi;
      const float dd = d * d * i2s;
      if (dd < GCUT) {
        const float g = __expf(-dd);
        const float2 v = src[f];
        acc.x += v.x * g; acc.y += v.y * g;
      }
    }
    Aw[swz(m)] = acc;
  }
  dif_w<M1, true, 64>(Aw, l);
#pragma unroll
  for (int i = 0; i < NRW; ++i) {
    const int m = l + 64 * i;
    const float2 zv = Aw[swz(m)];
    Aw[swz(m)] = make_float2(sqrtf(zv.x * zv.x + zv.y * zv.y) * (1.0f / 2048.0f), 0.0f);
  }
  dit_w<M1, 64>(Aw, l);  // V natural; KEEP.
  const float invM = 1.0f / (float)M1;
  const float c0 = Aw[0].x * invM;
  const float2 U1 = Aw[1], U2 = Aw[2];
  const float k1 = PHI1 * 2.0f * invM, k2 = PHI2 * 2.0f * invM;
  float part = 0.0f;
#pragma unroll
  for (int i = 0; i < NRW; ++i) {
    const int t = l + 64 * i;
    float sv, cv;
    __sincosf((6.283185307179586f / (float)M1) * (float)t, &sv, &cv);
    float acc = c0 + k1 * (U1.x * cv - U1.y * sv);
    const float c2 = cv * cv - sv * sv, s2 = 2.0f * sv * cv;
    acc += k2 * (U2.x * c2 - U2.y * s2);
    part += __logf(acc + 1e-6f);
  }
  part = wsum<64>(part);
  if (l == 0) out[((size_t)b * 440 + j1) * 6 + c] = part * invM;
}

// Parent, per-half-wave (32 lanes), M1=128. V stays in Ah.
__device__ __forceinline__ void parent_dual(float2* Ah, const float2* __restrict__ src,
                                            float* __restrict__ out,
                                            int b, int c, int j1, int ll) {
  const float xi = 0.4f * exp2f(-0.125f * (float)j1);
  const float sig = 0.1f * xi;
  const float i2s = 1.0f / (2.0f * sig * sig);
#pragma unroll
  for (int i = 0; i < 4; ++i) {
    const int m = ll + 32 * i;
    float2 acc = make_float2(0.0f, 0.0f);
#pragma unroll
    for (int q = 0; q < 16; ++q) {
      const int f = m + q * 128;
      const float fr = (float)(f < 1024 ? f : f - 2048) * (1.0f / 2048.0f);
      const float d = fr - xi;
      const float dd = d * d * i2s;
      if (dd < GCUT) {
        const float g = __expf(-dd);
        const float2 v = src[f];
        acc.x += v.x * g; acc.y += v.y * g;
      }
    }
    Ah[swz(m)] = acc;
  }
  dif_w<128, true, 32>(Ah, ll);
#pragma unroll
  for (int i = 0; i < 4; ++i) {
    const int m = ll + 32 * i;
    const float2 zv = Ah[swz(m)];
    Ah[swz(m)] = make_float2(sqrtf(zv.x * zv.x + zv.y * zv.y) * (1.0f / 2048.0f), 0.0f);
  }
  dit_w<128, 32>(Ah, ll);  // V natural; KEEP.
  const float invM = 1.0f / 128.0f;
  const float c0 = Ah[0].x * invM;
  const float2 U1 = Ah[1], U2 = Ah[2];
  const float k1 = PHI1 * 2.0f * invM, k2 = PHI2 * 2.0f * invM;
  float part = 0.0f;
#pragma unroll
  for (int i = 0; i < 4; ++i) {
    const int t = ll + 32 * i;
    float sv, cv;
    __sincosf((6.283185307179586f / 128.0f) * (float)t, &sv, &cv);
    float acc = c0 + k1 * (U1.x * cv - U1.y * sv);
    const float c2 = cv * cv - sv * sv, s2 = 2.0f * sv * cv;
    acc += k2 * (U2.x * c2 - U2.y * s2);
    part += __logf(acc + 1e-6f);
  }
  part = wsum<32>(part);
  if (ll == 0) out[((size_t)b * 440 + j1) * 6 + c] = part * invM;
}

// Descendant (second order), per-wave (64 lanes). V read from LDS (swizzled).
// NOTE: no cvs/svs caching — sincos is recomputed in the log pass. Caching
// cost NR2*2 VGPRs live across 5 wsum chains and spilled to scratch at the
// 64-VGPR tier (r1: WRITE_SIZE 7.36 MB vs 84 KB logical). Recompute is ~8 cyc.
template <int M2>
__device__ __forceinline__ void desc_wav(float2* Aw, const float2* __restrict__ Vl,
                                         float* __restrict__ outp, int M1, int F,
                                         float xi, int l) {
  constexpr int NR2 = M2 / 64;
  const float sg = 0.8f * xi;
  const float i2s = 1.0f / (2.0f * sg * sg);
#pragma unroll
  for (int ii = 0; ii < NR2; ++ii) {
    const int m = l + 64 * ii;
    float2 acc = make_float2(0.0f, 0.0f);
    for (int q = 0; q < F; ++q) {
      const int f = m + q * M2;
      const float fr = (float)(f < (M1 >> 1) ? f : f - M1) * (1.0f / 2048.0f);
      const float d = fr - xi;
      const float dd = d * d * i2s;
      if (dd < GCUT) {
        const float g = __expf(-dd);
        const float2 vv = Vl[swz(f)];
        acc.x += vv.x * g; acc.y += vv.y * g;
      }
    }
    Aw[swz(m)] = acc;
  }
  dif_w<M2, true, 64>(Aw, l);
  const float invM1f = 1.0f / (float)M1;
  float b0 = 0, b1r = 0, b1i = 0, b2r = 0, b2i = 0;
#pragma unroll
  for (int ii = 0; ii < NR2; ++ii) {
    const int idx = l + 64 * ii;
    const float2 zv = Aw[swz(idx)];
    const float u = sqrtf(zv.x * zv.x + zv.y * zv.y) * invM1f;
    const int t = prevM<M2>(idx);
    float sv, cv;
    __sincosf((6.283185307179586f / (float)M2) * (float)t, &sv, &cv);
    b0 += u;
    b1r += u * cv; b1i -= u * sv;
    const float c2 = cv * cv - sv * sv, s2 = 2.0f * sv * cv;
    b2r += u * c2; b2i -= u * s2;
  }
  b0 = wsum<64>(b0);
  b1r = wsum<64>(b1r); b1i = wsum<64>(b1i);
  b2r = wsum<64>(b2r); b2i = wsum<64>(b2i);
  const float k1 = 2.0f * PHI1, k2 = 2.0f * PHI2;
  const float invM2 = 1.0f / (float)M2;
  float part = 0.0f;
#pragma unroll
  for (int ii = 0; ii < NR2; ++ii) {
    const int idx = l + 64 * ii;
    const int t = prevM<M2>(idx);
    float sv, cv;
    __sincosf((6.283185307179586f / (float)M2) * (float)t, &sv, &cv);
    float acc = b0 + k1 * (b1r * cv - b1i * sv);
    const float c2 = cv * cv - sv * sv, s2 = 2.0f * sv * cv;
    acc += k2 * (b2r * c2 - b2i * s2);
    part += __logf(acc * invM2 + 1e-6f);
  }
  part = wsum<64>(part);
  if (l == 0) *outp = part * invM2;
}

// Descendant, per-half-wave (32 lanes), M2=128. V from LDS (swizzled).
// Same no-caching policy as desc_wav.
__device__ __forceinline__ void desc_dual(float2* Ah, const float2* __restrict__ Vl,
                                          float* __restrict__ outp, int M1, int F,
                                          float xi, int ll) {
  const float sg = 0.8f * xi;
  const float i2s = 1.0f / (2.0f * sg * sg);
#pragma unroll
  for (int ii = 0; ii < 4; ++ii) {
    const int m = ll + 32 * ii;
    float2 acc = make_float2(0.0f, 0.0f);
    for (int q = 0; q < F; ++q) {
      const int f = m + q * 128;
      const float fr = (float)(f < (M1 >> 1) ? f : f - M1) * (1.0f / 2048.0f);
      const float d = fr - xi;
      const float dd = d * d * i2s;
      if (dd < GCUT) {
        const float g = __expf(-dd);
        const float2 vv = Vl[swz(f)];
        acc.x += vv.x * g; acc.y += vv.y * g;
      }
    }
    Ah[swz(m)] = acc;
  }
  dif_w<128, true, 32>(Ah, ll);
  const float invM1f = 1.0f / (float)M1;
  float b0 = 0, b1r = 0, b1i = 0, b2r = 0, b2i = 0;
#pragma unroll
  for (int ii = 0; ii < 4; ++ii) {
    const int idx = ll + 32 * ii;
    const float2 zv = Ah[swz(idx)];
    const float u = sqrtf(zv.x * zv.x + zv.y * zv.y) * invM1f;
    const int t = prevM<128>(idx);
    float sv, cv;
    __sincosf((6.283185307179586f / 128.0f) * (float)t, &sv, &cv);
    b0 += u;
    b1r += u * cv; b1i -= u * sv;
    const float c2 = cv * cv - sv * sv, s2 = 2.0f * sv * cv;
    b2r += u * c2; b2i -= u * s2;
  }
  b0 = wsum<32>(b0);
  b1r = wsum<32>(b1r); b1i = wsum<32>(b1i);
  b2r = wsum<32>(b2r); b2i = wsum<32>(b2i);
  const float k1 = 2.0f * PHI1, k2 = 2.0f * PHI2;
  const float invM2 = 1.0f / 128.0f;
  float part = 0.0f;
#pragma unroll
  for (int ii = 0; ii < 4; ++ii) {
    const int idx = ll + 32 * ii;
    const int t = prevM<128>(idx);
    float sv, cv;
    __sincosf((6.283185307179586f / 128.0f) * (float)t, &sv, &cv);
    float acc = b0 + k1 * (b1r * cv - b1i * sv);
    const float c2 = cv * cv - sv * sv, s2 = 2.0f * sv * cv;
    acc += k2 * (b2r * c2 - b2i * s2);
    part += __logf(acc * invM2 + 1e-6f);
  }
  part = wsum<32>(part);
  if (ll == 0) *outp = part * invM2;
}

// S2 output pointer for pair (j1, k): p = 4k(k-1)+j1.
__device__ __forceinline__ float* o2p(float* out, int b, int c, int j1, int k) {
  return out + ((size_t)b * 440 + 80 + 4 * k * (k - 1) + j1) * 6 + c;
}
__device__ __forceinline__ float xi2f(int k) { return 0.4f * exp2f(-(float)k); }

// kBC: 19 classes/signal. ci map (heavy-serial first):
//  [0,2)  o=1 (M1=512):  4 j1 per block (wave-private), j1 = 8+4*ci+wid.
//         desc: k2(512), k3(256) full-wave; k4..k9 (128) split 3/3 on halves.
//  [2,4)  o=2 (M1=256):  j1 = 16+4*(ci-2)+wid. desc: k3(256); k4..k9 split 3/3.
//  [4,12) o=0 (M1=1024): block-wide parent, j1 = ci-4.
//         desc: w0:{k1(1024)} w1:{k2(512),k5/k6} w2:{k3(512),k7/k8}
//               w3:{k4(256), h0:k9}.
//  [12,19) o=3..9 (M1=128): 8 paths/block on half-waves, j1 = 8o+2*wid+h;
//         desc k=o+1..9, all 128-pt, per-half.
// LDS: 4096 float2 = 32 KB -> 5 blocks/CU; grid needs 912/256 = 3.6 blocks/CU.
__global__ __launch_bounds__(NTH, 4) void kBC(const float2* __restrict__ xh,
                                              float* __restrict__ out) {
  __shared__ float2 L[4096];  // 32768 B
  const int ci = (int)blockIdx.x / 48;
  const int n  = (int)blockIdx.x % 48;
  const int b = n / 6, c = n % 6;
  const float2* src = xh + (size_t)n * 2048;
  const int tid = (int)threadIdx.x;
  const int wid = tid >> 6, l = tid & 63;
  const int h = l >> 5, ll = l & 31;

  if (ci < 2) {  // ---- o=1, M1=512, wave-private ----
    const int j1 = 8 + 4 * ci + wid;
    float2* Aw = L + wid * 1024;   // parent V: [0,512) of slice
    float2* W  = Aw + 512;         // descendant work: [512,1024)
    parent_wav<512>(Aw, src, out, b, c, j1, l);
    desc_wav<512>(W, Aw, o2p(out, b, c, j1, 2), 512, 1, xi2f(2), l);
    desc_wav<256>(W, Aw, o2p(out, b, c, j1, 3), 512, 2, xi2f(3), l);
    float2* Wh = W + h * 128;
    for (int i = 0; i < 3; ++i) {
      const int k = 4 + 2 * i + h;  // h0: k4,k6,k8  h1: k5,k7,k9
      desc_dual(Wh, Aw, o2p(out, b, c, j1, k), 512, 4, xi2f(k), ll);
    }
  } else if (ci < 4) {  // ---- o=2, M1=256, wave-private ----
    const int j1 = 16 + 4 * (ci - 2) + wid;
    float2* Aw = L + wid * 512;
    float2* W  = Aw + 256;
    parent_wav<256>(Aw, src, out, b, c, j1, l);
    desc_wav<256>(W, Aw, o2p(out, b, c, j1, 3), 256, 1, xi2f(3), l);
    float2* Wh = W + h * 128;
    for (int i = 0; i < 3; ++i) {
      const int k = 4 + 2 * i + h;
      desc_dual(Wh, Aw, o2p(out, b, c, j1, k), 256, 2, xi2f(k), ll);
    }
  } else if (ci < 12) {  // ---- o=0, M1=1024, block-wide parent ----
    const int j1 = ci - 4;
    float* scr = (float*)(L + 3968);  // [3968,4096) reserved for scratch
    parent_blk1024(L, scr, src, out, b, c, j1);
    // parent ends after a block-wide __syncthreads; V final in L[0,1024).
    if (wid == 0) {
      desc_wav<1024>(L + 1024, L, o2p(out, b, c, j1, 1), 1024, 1, xi2f(1), l);
    } else if (wid == 1) {
      desc_wav<512>(L + 2048, L, o2p(out, b, c, j1, 2), 1024, 2, xi2f(2), l);
      const int k = 5 + h;
      desc_dual(L + 3328 + h * 128, L, o2p(out, b, c, j1, k), 1024, 8, xi2f(k), ll);
    } else if (wid == 2) {
      desc_wav<512>(L + 2560, L, o2p(out, b, c, j1, 3), 1024, 2, xi2f(3), l);
      const int k = 7 + h;
      desc_dual(L + 3584 + h * 128, L, o2p(out, b, c, j1, k), 1024, 8, xi2f(k), ll);
    } else {
      desc_wav<256>(L + 3072, L, o2p(out, b, c, j1, 4), 1024, 4, xi2f(4), l);
      if (h == 0)
        desc_dual(L + 3840, L, o2p(out, b, c, j1, 9), 1024, 8, xi2f(9), ll);
    }
  } else {  // ---- o=3..9, M1=128, half-wave-private ----
    const int o = ci - 9;  // 3..9
    const int j1 = 8 * o + 2 * wid + h;
    float2* Ah = L + (2 * wid + h) * 256;  // parent [0,128), work [128,256)
    parent_dual(Ah, src, out, b, c, j1, ll);
    float2* W = Ah + 128;
    for (int k = o + 1; k <= 9; ++k)
      desc_dual(W, Ah, o2p(out, b, c, j1, k), 128, 1, xi2f(k), ll);
  }
}

extern "C" void kernel_launch(void* const* d_in, const int* in_sizes, int n_in,
                              void* d_out, int out_size, void* d_ws, size_t ws_size,
                              hipStream_t stream) {
  (void)in_sizes; (void)n_in; (void)out_size; (void)ws_size;
  const float* x = (const float*)d_in[0];  // [8, 2048, 6] fp32
  float* out = (float*)d_out;              // [8, 440, 6] fp32
  float2* xh = (float2*)d_ws;              // 48 * 2048 * 8 B = 786 KB
  kA<<<dim3(48), dim3(NTH), 0, stream>>>(x, xh);
  kBC<<<dim3(19 * 48), dim3(NTH), 0, stream>>>(xh, out);
}